// Round 1
// baseline (4495.306 us; speedup 1.0000x reference)
//
#include <hip/hip_runtime.h>
#include <math.h>

#define VOCAB 32000
#define H 256
#define BATCH 16
#define T 512
#define NT 6
#define START 4
#define STOP 5
#define NEGV -10000.0f

// ws layout (floats):
// [0, 262144)              WhhT  [256][1024]  (k-major transpose of W_hh)
// [262144, 524288)         WihT  [256][1024]
// [524288, 524288+8388608) Xp    [B*T][1024]  (input projections + bias)

__global__ void transpose_w(const float* __restrict__ W_ih, const float* __restrict__ W_hh,
                            float* __restrict__ WihT, float* __restrict__ WhhT) {
    int o = blockIdx.x * blockDim.x + threadIdx.x;
    if (o >= 256 * 1024) return;
    int k = o >> 10;
    int g = o & 1023;
    WihT[o] = W_ih[g * 256 + k];
    WhhT[o] = W_hh[g * 256 + k];
}

// One block = 16 (b,t) rows, 1024 threads = 1 thread per gate.
__global__ __launch_bounds__(1024) void input_proj(const int* __restrict__ sentence,
                                                   const float* __restrict__ embedding,
                                                   const float* __restrict__ WihT,
                                                   const float* __restrict__ b_ih,
                                                   const float* __restrict__ b_hh,
                                                   float* __restrict__ Xp) {
    __shared__ __align__(16) float emb[16][260];  // row stride 260*4=1040B (16B aligned)
    int tid = threadIdx.x;
    int bt0 = blockIdx.x * 16;
    {
        int r = tid >> 6, j = tid & 63;
        int row = sentence[bt0 + r];
        const float4* src = (const float4*)(embedding + (size_t)row * 256);
        float4 v = src[j];
        float* dst = &emb[r][j * 4];
        dst[0] = v.x; dst[1] = v.y; dst[2] = v.z; dst[3] = v.w;
    }
    __syncthreads();
    int g = tid;
    float bias = b_ih[g] + b_hh[g];
    float acc[16];
#pragma unroll
    for (int r = 0; r < 16; r++) acc[r] = bias;
    const float* wp = WihT + g;
    for (int k4 = 0; k4 < 64; k4++) {
        float w0 = wp[(k4 * 4 + 0) * 1024];
        float w1 = wp[(k4 * 4 + 1) * 1024];
        float w2 = wp[(k4 * 4 + 2) * 1024];
        float w3 = wp[(k4 * 4 + 3) * 1024];
#pragma unroll
        for (int r = 0; r < 16; r++) {
            float4 e = *(const float4*)&emb[r][k4 * 4];
            acc[r] += w0 * e.x + w1 * e.y + w2 * e.z + w3 * e.w;
        }
    }
#pragma unroll
    for (int r = 0; r < 16; r++) Xp[(size_t)(bt0 + r) * 1024 + g] = acc[r];
}

// One block per batch element. 1024 threads = 1 per gate.
// Fused: LSTM recurrence + output projection (feats) + CRF-Viterbi forward + backtrack.
__global__ __launch_bounds__(1024) void lstm_crf(const float* __restrict__ WhhT,
                                                 const float* __restrict__ Xp,
                                                 const float* __restrict__ W_out,
                                                 const float* __restrict__ b_out,
                                                 const float* __restrict__ trans,
                                                 float* __restrict__ out) {
    __shared__ __align__(16) float h_lds[256];
    __shared__ float gates_lds[1024];
    __shared__ __align__(16) float wout_lds[6 * 256];
    __shared__ float feat_lds[6];
    __shared__ float trans_lds[36];
    __shared__ unsigned bp_lds[512];

    int tid = threadIdx.x;
    int b = blockIdx.x;

    if (tid < 256) h_lds[tid] = 0.f;
    for (int i = tid; i < 6 * 256; i += 1024) wout_lds[i] = W_out[i];
    if (tid < 36) trans_lds[tid] = trans[tid];
    float c_reg = 0.f;
    float fv[6];
    if (tid == 0) {
#pragma unroll
        for (int i = 0; i < 6; i++) fv[i] = (i == START) ? 0.f : NEGV;
    }
    __syncthreads();

    const float* wp = WhhT + tid;
    const float* xp = Xp + (size_t)b * T * 1024 + tid;

    for (int t = 0; t < T; t++) {
        // Phase 1: gates = Xp + h @ WhhT (per-thread dot of length 256) + activation
        float acc = xp[(size_t)t * 1024];
#pragma unroll 4
        for (int k4 = 0; k4 < 64; k4++) {
            float4 hv = *(const float4*)&h_lds[k4 * 4];
            acc += wp[(k4 * 4 + 0) * 1024] * hv.x;
            acc += wp[(k4 * 4 + 1) * 1024] * hv.y;
            acc += wp[(k4 * 4 + 2) * 1024] * hv.z;
            acc += wp[(k4 * 4 + 3) * 1024] * hv.w;
        }
        int gtype = tid >> 8;  // 0:i 1:f 2:g 3:o
        float val = (gtype == 2) ? tanhf(acc) : 1.f / (1.f + expf(-acc));
        gates_lds[tid] = val;
        __syncthreads();  // A: gates ready; h reads of this step done

        // Phase 2: c/h update
        if (tid < 256) {
            float iv = gates_lds[tid];
            float fg = gates_lds[256 + tid];
            float gv = gates_lds[512 + tid];
            float ov = gates_lds[768 + tid];
            c_reg = fg * c_reg + iv * gv;
            h_lds[tid] = ov * tanhf(c_reg);
        }
        __syncthreads();  // B: h_t ready

        // Phase 3: feats[w] = h . W_out[w] + b_out[w], one wave per tag
        if (tid < 384) {
            int w = tid >> 6, lane = tid & 63;
            float4 hh = *(const float4*)&h_lds[lane * 4];
            float4 ww = *(const float4*)&wout_lds[w * 256 + lane * 4];
            float p = hh.x * ww.x + hh.y * ww.y + hh.z * ww.z + hh.w * ww.w;
#pragma unroll
            for (int off = 32; off; off >>= 1) p += __shfl_down(p, off);
            if (lane == 0) feat_lds[w] = p + b_out[w];
        }
        __syncthreads();  // C: feats ready

        // Phase 4: CRF forward step (thread 0), overlaps others' next phase-1
        if (tid == 0) {
            unsigned packed = 0;
            float nfv[6];
#pragma unroll
            for (int nx = 0; nx < 6; nx++) {
                float best = fv[0] + trans_lds[nx * 6 + 0];
                int arg = 0;
#pragma unroll
                for (int pv = 1; pv < 6; pv++) {
                    float s = fv[pv] + trans_lds[nx * 6 + pv];
                    if (s > best) { best = s; arg = pv; }  // strict >: first-max like np.argmax
                }
                nfv[nx] = best + feat_lds[nx];
                packed |= (unsigned)arg << (3 * nx);
            }
#pragma unroll
            for (int i = 0; i < 6; i++) fv[i] = nfv[i];
            bp_lds[t] = packed;
        }
    }

    // Terminal + backtrack
    if (tid == 0) {
        float best = fv[0] + trans_lds[STOP * 6 + 0];
        int arg = 0;
#pragma unroll
        for (int tg = 1; tg < 6; tg++) {
            float s = fv[tg] + trans_lds[STOP * 6 + tg];
            if (s > best) { best = s; arg = tg; }
        }
        out[b] = best;  // path score
        int tag = arg;
        float* paths = out + 16 + (size_t)b * 512;
        for (int t = T - 1; t >= 0; t--) {
            paths[t] = (float)tag;
            tag = (bp_lds[t] >> (3 * tag)) & 7;
        }
    }
}

extern "C" void kernel_launch(void* const* d_in, const int* in_sizes, int n_in,
                              void* d_out, int out_size, void* d_ws, size_t ws_size,
                              hipStream_t stream) {
    const int* sentence = (const int*)d_in[0];
    const float* embedding = (const float*)d_in[1];
    const float* W_ih = (const float*)d_in[2];
    const float* W_hh = (const float*)d_in[3];
    const float* b_ih = (const float*)d_in[4];
    const float* b_hh = (const float*)d_in[5];
    const float* W_out = (const float*)d_in[6];
    const float* b_out = (const float*)d_in[7];
    const float* trans = (const float*)d_in[8];
    float* out = (float*)d_out;
    float* ws = (float*)d_ws;

    float* WhhT = ws;
    float* WihT = ws + 262144;
    float* Xp = ws + 524288;

    hipLaunchKernelGGL(transpose_w, dim3(1024), dim3(256), 0, stream, W_ih, W_hh, WihT, WhhT);
    hipLaunchKernelGGL(input_proj, dim3(BATCH * T / 16), dim3(1024), 0, stream,
                       sentence, embedding, WihT, b_ih, b_hh, Xp);
    hipLaunchKernelGGL(lstm_crf, dim3(BATCH), dim3(1024), 0, stream,
                       WhhT, Xp, W_out, b_out, trans, out);
}